// Round 1
// 167.691 us; speedup vs baseline: 1.0642x; 1.0642x over previous
//
#include <hip/hip_runtime.h>

// ---------------- types / helpers ----------------
using bf16x8 = __attribute__((ext_vector_type(8))) short;
using f32x4  = __attribute__((ext_vector_type(4))) float;

static __device__ inline unsigned short f2bf(float f) {
  unsigned int u = __float_as_uint(f);
  u += 0x7fffu + ((u >> 16) & 1u);          // round-to-nearest-even
  return (unsigned short)(u >> 16);
}
static __device__ inline unsigned int pk2(float a, float b) {
  return (unsigned int)f2bf(a) | ((unsigned int)f2bf(b) << 16);
}

// butterfly reductions across the 16-lane DPP row (row_ror 1,2,4,8)
#define ROW16_MAX(x) { \
  { int _t = __builtin_amdgcn_update_dpp(0, __float_as_int(x), 0x121, 0xf, 0xf, true); x = fmaxf(x, __int_as_float(_t)); } \
  { int _t = __builtin_amdgcn_update_dpp(0, __float_as_int(x), 0x122, 0xf, 0xf, true); x = fmaxf(x, __int_as_float(_t)); } \
  { int _t = __builtin_amdgcn_update_dpp(0, __float_as_int(x), 0x124, 0xf, 0xf, true); x = fmaxf(x, __int_as_float(_t)); } \
  { int _t = __builtin_amdgcn_update_dpp(0, __float_as_int(x), 0x128, 0xf, 0xf, true); x = fmaxf(x, __int_as_float(_t)); } }
#define ROW16_SUM(x) { \
  { int _t = __builtin_amdgcn_update_dpp(0, __float_as_int(x), 0x121, 0xf, 0xf, true); x += __int_as_float(_t); } \
  { int _t = __builtin_amdgcn_update_dpp(0, __float_as_int(x), 0x122, 0xf, 0xf, true); x += __int_as_float(_t); } \
  { int _t = __builtin_amdgcn_update_dpp(0, __float_as_int(x), 0x124, 0xf, 0xf, true); x += __int_as_float(_t); } \
  { int _t = __builtin_amdgcn_update_dpp(0, __float_as_int(x), 0x128, 0xf, 0xf, true); x += __int_as_float(_t); } }

// ---------------- kernel 0: weight prep (transpose -> bf16) ----------------
__global__ __launch_bounds__(256) void prep_kernel(
    const float* __restrict__ Wq, const float* __restrict__ Wk, const float* __restrict__ Wv,
    const float* __restrict__ Wo, const float* __restrict__ bq, const float* __restrict__ bk,
    const float* __restrict__ bv,
    unsigned short* __restrict__ Wt, unsigned short* __restrict__ Wot, float* __restrict__ bqkv)
{
  int idx = blockIdx.x * 256 + threadIdx.x;
  if (idx < 192 * 1024) {
    int n = idx >> 10, k = idx & 1023;
    const float* W = (n < 64) ? Wq : (n < 128) ? Wk : Wv;
    Wt[idx] = f2bf(W[k * 64 + (n & 63)]);
  } else if (idx < 192 * 1024 + 1024 * 64) {
    int j = idx - 192 * 1024;
    int n = j >> 6, k = j & 63;
    Wot[j] = f2bf(Wo[k * 1024 + n]);
  } else if (idx < 192 * 1024 + 1024 * 64 + 192) {
    int n = idx - (192 * 1024 + 1024 * 64);
    bqkv[n] = (n < 64) ? bq[n] : (n < 128) ? bk[n - 64] : bv[n - 128];
  }
}

// ---------------- kernel 1: QKV projection (bf16 MFMA), pipelined ----------------
// X [16384][1024] fp32, Wt [192][1024] bf16 -> qkvb [16384][192] bf16
// BM=32, BN=96 (N split in 2), BK=64; grid 1024 -> 4 blocks/CU.
// Software pipeline: double-buffered LDS, ONE barrier per K-step, next tile's
// global loads issued before the barrier (reg loads survive s_barrier; only
// LDS ops force the waitcnt drain). Latency hides under barrier+MFMA+store.
__global__ __launch_bounds__(256) void qkv_gemm(
    const float* __restrict__ X, const unsigned short* __restrict__ Wt,
    const float* __restrict__ bqkv, unsigned short* __restrict__ qkvb)
{
  __shared__ __align__(16) unsigned short As[2][32 * 72];
  __shared__ __align__(16) unsigned short Bs[2][96 * 72];
  int t = threadIdx.x;
  int lane = t & 63, w = t >> 6;
  int m0 = (blockIdx.x >> 1) * 32;
  int nbase = (blockIdx.x & 1) * 96;
  int mg = w & 1, ng = w >> 1;               // wave: 16 rows x 48 cols
  int col = lane & 15, quad = lane >> 4;
  f32x4 acc[3] = {};

  int rowA = t >> 3, cA = t & 7;
  const float* srcA = X + (size_t)(m0 + rowA) * 1024 + cA * 8;
  const unsigned short* srcB = Wt + (size_t)(nbase + rowA) * 1024 + cA * 8;

  // prologue: prefetch tile 0 into registers
  float4 f0 = *(const float4*)(srcA);
  float4 f1 = *(const float4*)(srcA + 4);
  uint4 b0 = *(const uint4*)(srcB);
  uint4 b1 = *(const uint4*)(srcB + 32 * 1024);
  uint4 b2 = *(const uint4*)(srcB + 64 * 1024);

  for (int ks = 0; ks < 16; ++ks) {
    int cur = ks & 1;
    { // store staged regs -> LDS[cur]
      uint4 p;
      p.x = pk2(f0.x, f0.y); p.y = pk2(f0.z, f0.w);
      p.z = pk2(f1.x, f1.y); p.w = pk2(f1.z, f1.w);
      *(uint4*)(As[cur] + rowA * 72 + cA * 8) = p;
      *(uint4*)(Bs[cur] + rowA * 72 + cA * 8) = b0;
      *(uint4*)(Bs[cur] + (rowA + 32) * 72 + cA * 8) = b1;
      *(uint4*)(Bs[cur] + (rowA + 64) * 72 + cA * 8) = b2;
    }
    if (ks < 15) { // issue next tile's loads BEFORE the barrier
      const float* sA = srcA + (ks + 1) * 64;
      f0 = *(const float4*)(sA);
      f1 = *(const float4*)(sA + 4);
      const unsigned short* sB = srcB + (ks + 1) * 64;
      b0 = *(const uint4*)(sB);
      b1 = *(const uint4*)(sB + 32 * 1024);
      b2 = *(const uint4*)(sB + 64 * 1024);
    }
    __syncthreads();
    #pragma unroll
    for (int kk = 0; kk < 64; kk += 32) {
      int ko = kk + quad * 8;
      bf16x8 a = *(const bf16x8*)(As[cur] + (mg * 16 + col) * 72 + ko);
      #pragma unroll
      for (int ns = 0; ns < 3; ++ns) {
        bf16x8 b = *(const bf16x8*)(Bs[cur] + ((ng * 3 + ns) * 16 + col) * 72 + ko);
        acc[ns] = __builtin_amdgcn_mfma_f32_16x16x32_bf16(a, b, acc[ns], 0, 0, 0);
      }
    }
    // single barrier/iter is race-free: iter t+2's store to buf[cur] is
    // separated from iter t's reads of buf[cur] by barrier t+1.
  }
  #pragma unroll
  for (int ns = 0; ns < 3; ++ns)
    #pragma unroll
    for (int r = 0; r < 4; ++r) {
      int m = m0 + mg * 16 + quad * 4 + r;
      int n = nbase + ng * 48 + ns * 16 + col;
      qkvb[(size_t)m * 192 + n] = f2bf(acc[ns][r] + bqkv[n]);
    }
}

// ---------------- kernel 2: banded flash attention (MFMA) ----------------
// Exact: out-of-band exp underflows to 0; padding mask softmax-invariant.
// qkv now bf16 -> staging is pure copies (no f2bf), half the bytes.
__global__ __launch_bounds__(256) void band_attn(
    const unsigned short* __restrict__ qkvb, const float* __restrict__ bias,
    unsigned short* __restrict__ attnout)
{
  __shared__ __align__(16) unsigned short Kl[192 * 72];
  __shared__ __align__(16) unsigned short Vt[64 * 216];
  __shared__ __align__(16) unsigned short Ps[4 * 16 * 168];
  __shared__ float biasL[129];

  int t = threadIdx.x;
  int lane = t & 63, w = t >> 6;
  int col = lane & 15, quad = lane >> 4;
  int bidx = blockIdx.x;
  int b = bidx >> 5;                 // batch
  int i0 = (bidx & 31) * 64;         // first q row (batch coords)
  int jw = i0 - 64;                  // window start (may be <0)
  const unsigned short* qbase = qkvb + (size_t)(b << 11) * 192;

  // Q fragments: issue global loads FIRST so they overlap the staging loop
  int iq = i0 + w * 16;                    // wave's first q row (batch coords)
  const unsigned short* qr = qbase + (size_t)(iq + col) * 192 + quad * 8;
  bf16x8 aq0 = *(const bf16x8*)(qr);
  bf16x8 aq1 = *(const bf16x8*)(qr + 32);

  if (t < 129) biasL[t] = bias[1984 + t];
  // stage window: 192 rows x (64 K + 64 V) bf16 = 16 chunks of 16B per row
  #pragma unroll
  for (int it = 0; it < 12; ++it) {
    int idx = it * 256 + t;
    int row = idx >> 4;                    // 0..191 window row
    int c = idx & 15;                      // 16B chunk within k|v
    int jb = jw + row;
    int jc = jb < 0 ? 0 : (jb > 2047 ? 2047 : jb);
    const unsigned short* src = qbase + (size_t)jc * 192 + 64 + c * 8;
    uint4 v = *(const uint4*)src;
    if (c < 8) {                           // K: direct copy
      *(uint4*)(Kl + row * 72 + c * 8) = v;
    } else {                               // V: transpose store
      union { uint4 u; unsigned short s[8]; } uv; uv.u = v;
      int p0 = (c - 8) * 8;
      #pragma unroll
      for (int e = 0; e < 8; ++e) Vt[(p0 + e) * 216 + row] = uv.s[e];
    }
  }
  { // zero-fill Vt j-cols 192..207 (PV k-chunk overhang)
    int p = t >> 2, c0 = 192 + (t & 3) * 4;
    *(uint2*)(Vt + p * 216 + c0) = make_uint2(0u, 0u);
  }
  __syncthreads();

  // QK^T: 9 j-tiles
  f32x4 s[9];
  #pragma unroll
  for (int t9 = 0; t9 < 9; ++t9) {
    int krow = ((w + t9) * 16 + col) * 72;
    bf16x8 kb0 = *(const bf16x8*)(Kl + krow + quad * 8);
    bf16x8 kb1 = *(const bf16x8*)(Kl + krow + 32 + quad * 8);
    f32x4 z = {};
    z = __builtin_amdgcn_mfma_f32_16x16x32_bf16(aq0, kb0, z, 0, 0, 0);
    s[t9] = __builtin_amdgcn_mfma_f32_16x16x32_bf16(aq1, kb1, z, 0, 0, 0);
  }
  // mask + bias; row max
  int q4 = quad * 4;
  float mrow[4] = {-3e38f, -3e38f, -3e38f, -3e38f};
  #pragma unroll
  for (int t9 = 0; t9 < 9; ++t9) {
    int j = iq - 64 + t9 * 16 + col;       // batch coords
    #pragma unroll
    for (int r = 0; r < 4; ++r) {
      int diff = q4 + r + 64 - t9 * 16 - col;   // i - j
      bool valid = (j >= 0) & (j < 2048) & (diff >= -64) & (diff <= 64);
      int bi = 64 - diff; bi = bi < 0 ? 0 : (bi > 128 ? 128 : bi);
      float sv = valid ? (s[t9][r] * 0.125f + biasL[bi]) : -3e38f;
      s[t9][r] = sv;
      mrow[r] = fmaxf(mrow[r], sv);
    }
  }
  #pragma unroll
  for (int r = 0; r < 4; ++r) ROW16_MAX(mrow[r]);
  unsigned short* Pw = Ps + w * (16 * 168);
  float lsum[4] = {0.f, 0.f, 0.f, 0.f};
  #pragma unroll
  for (int t9 = 0; t9 < 9; ++t9)
    #pragma unroll
    for (int r = 0; r < 4; ++r) {
      float p = __expf(s[t9][r] - mrow[r]);
      lsum[r] += p;
      Pw[(q4 + r) * 168 + t9 * 16 + col] = f2bf(p);
    }
  #pragma unroll
  for (int r = 0; r < 4; ++r) {
    ROW16_SUM(lsum[r]);
    Pw[(q4 + r) * 168 + 144 + col] = 0;    // zero-pad k-cols 144..159
  }
  // PV: O[16 q][64 p] = P(16x160) . V(160x64)
  f32x4 o[4] = {};
  #pragma unroll
  for (int kc = 0; kc < 5; ++kc) {
    bf16x8 pa = *(const bf16x8*)(Pw + col * 168 + kc * 32 + quad * 8);
    #pragma unroll
    for (int nt = 0; nt < 4; ++nt) {
      bf16x8 vb = *(const bf16x8*)(Vt + (nt * 16 + col) * 216 + 16 * w + kc * 32 + quad * 8);
      o[nt] = __builtin_amdgcn_mfma_f32_16x16x32_bf16(pa, vb, o[nt], 0, 0, 0);
    }
  }
  float rl[4];
  #pragma unroll
  for (int r = 0; r < 4; ++r) rl[r] = 1.0f / lsum[r];
  #pragma unroll
  for (int nt = 0; nt < 4; ++nt)
    #pragma unroll
    for (int r = 0; r < 4; ++r) {
      int arow = (b << 11) + iq + q4 + r;
      attnout[(size_t)arow * 64 + nt * 16 + col] = f2bf(o[nt][r] * rl[r]);
    }
}

// ---------------- kernel 3: output projection (bf16 MFMA) + bias ----------------
__global__ __launch_bounds__(256) void out_gemm(
    const unsigned short* __restrict__ attn, const unsigned short* __restrict__ Wot,
    const float* __restrict__ bo, float* __restrict__ out)
{
  __shared__ __align__(16) unsigned short As[64 * 72];
  __shared__ __align__(16) unsigned short Bs[128 * 72];
  int t = threadIdx.x, lane = t & 63, w = t >> 6;
  int m0 = (blockIdx.x >> 3) * 64;
  int n0 = (blockIdx.x & 7) * 128;
  #pragma unroll
  for (int r = 0; r < 2; ++r) {            // stage A: 64x64 bf16
    int tau = t + 256 * r; int row = tau >> 3, c = tau & 7;
    *(uint4*)(As + row * 72 + c * 8) =
        *(const uint4*)(attn + (size_t)(m0 + row) * 64 + c * 8);
  }
  #pragma unroll
  for (int r = 0; r < 4; ++r) {            // stage B: 128x64 bf16
    int tau = t + 256 * r; int n = tau >> 3, c = tau & 7;
    *(uint4*)(Bs + n * 72 + c * 8) =
        *(const uint4*)(Wot + (size_t)(n0 + n) * 64 + c * 8);
  }
  __syncthreads();
  f32x4 acc[2][4] = {};
  int mg = w & 1, ngg = w >> 1;
  #pragma unroll
  for (int kk = 0; kk < 64; kk += 32) {
    int ko = kk + (lane >> 4) * 8;
    bf16x8 a0 = *(const bf16x8*)(As + (mg * 32 +      (lane & 15)) * 72 + ko);
    bf16x8 a1 = *(const bf16x8*)(As + (mg * 32 + 16 + (lane & 15)) * 72 + ko);
    #pragma unroll
    for (int ns = 0; ns < 4; ++ns) {
      bf16x8 b = *(const bf16x8*)(Bs + ((ngg * 4 + ns) * 16 + (lane & 15)) * 72 + ko);
      acc[0][ns] = __builtin_amdgcn_mfma_f32_16x16x32_bf16(a0, b, acc[0][ns], 0, 0, 0);
      acc[1][ns] = __builtin_amdgcn_mfma_f32_16x16x32_bf16(a1, b, acc[1][ns], 0, 0, 0);
    }
  }
  int col = lane & 15, q = lane >> 4;
  #pragma unroll
  for (int ms = 0; ms < 2; ++ms)
    #pragma unroll
    for (int ns = 0; ns < 4; ++ns)
      #pragma unroll
      for (int r = 0; r < 4; ++r) {
        int mm = m0 + mg * 32 + ms * 16 + q * 4 + r;
        int nn = n0 + (ngg * 4 + ns) * 16 + col;
        out[(size_t)mm * 1024 + nn] = acc[ms][ns][r] + bo[nn];
      }
}

// ---------------- launch ----------------
extern "C" void kernel_launch(void* const* d_in, const int* in_sizes, int n_in,
                              void* d_out, int out_size, void* d_ws, size_t ws_size,
                              hipStream_t stream) {
  const float* X    = (const float*)d_in[0];
  // d_in[1] = attention_mask: per-row constant shift -> softmax-invariant, unused
  const float* Wq   = (const float*)d_in[2];
  const float* bq   = (const float*)d_in[3];
  const float* Wk   = (const float*)d_in[4];
  const float* bk   = (const float*)d_in[5];
  const float* Wv   = (const float*)d_in[6];
  const float* bv   = (const float*)d_in[7];
  const float* Wo   = (const float*)d_in[8];
  const float* bo   = (const float*)d_in[9];
  const float* bias = (const float*)d_in[10];
  float* out = (float*)d_out;
  char* ws = (char*)d_ws;
  unsigned short* qkvb = (unsigned short*)(ws);              // 6,291,456 B
  unsigned short* attn = (unsigned short*)(ws + 6291456);    // 2,097,152 B
  unsigned short* Wt   = (unsigned short*)(ws + 8388608);    //   393,216 B
  unsigned short* Wot  = (unsigned short*)(ws + 8781824);    //   131,072 B
  float*          bqkv = (float*)(ws + 8912896);             //       768 B

  prep_kernel<<<1025, 256, 0, stream>>>(Wq, Wk, Wv, Wo, bq, bk, bv, Wt, Wot, bqkv);
  qkv_gemm<<<1024, 256, 0, stream>>>(X, Wt, bqkv, qkvb);
  band_attn<<<256, 256, 0, stream>>>(qkvb, bias, attn);
  out_gemm<<<2048, 256, 0, stream>>>(attn, Wot, bo, out);
}

// Round 2
// 167.481 us; speedup vs baseline: 1.0655x; 1.0013x over previous
//
#include <hip/hip_runtime.h>

// ---------------- types / helpers ----------------
using bf16x8 = __attribute__((ext_vector_type(8))) short;
using f32x4  = __attribute__((ext_vector_type(4))) float;

static __device__ inline unsigned short f2bf(float f) {
  unsigned int u = __float_as_uint(f);
  u += 0x7fffu + ((u >> 16) & 1u);          // round-to-nearest-even
  return (unsigned short)(u >> 16);
}
static __device__ inline unsigned int pk2(float a, float b) {
  return (unsigned int)f2bf(a) | ((unsigned int)f2bf(b) << 16);
}

// butterfly reductions across the 16-lane DPP row (row_ror 1,2,4,8)
#define ROW16_MAX(x) { \
  { int _t = __builtin_amdgcn_update_dpp(0, __float_as_int(x), 0x121, 0xf, 0xf, true); x = fmaxf(x, __int_as_float(_t)); } \
  { int _t = __builtin_amdgcn_update_dpp(0, __float_as_int(x), 0x122, 0xf, 0xf, true); x = fmaxf(x, __int_as_float(_t)); } \
  { int _t = __builtin_amdgcn_update_dpp(0, __float_as_int(x), 0x124, 0xf, 0xf, true); x = fmaxf(x, __int_as_float(_t)); } \
  { int _t = __builtin_amdgcn_update_dpp(0, __float_as_int(x), 0x128, 0xf, 0xf, true); x = fmaxf(x, __int_as_float(_t)); } }
#define ROW16_SUM(x) { \
  { int _t = __builtin_amdgcn_update_dpp(0, __float_as_int(x), 0x121, 0xf, 0xf, true); x += __int_as_float(_t); } \
  { int _t = __builtin_amdgcn_update_dpp(0, __float_as_int(x), 0x122, 0xf, 0xf, true); x += __int_as_float(_t); } \
  { int _t = __builtin_amdgcn_update_dpp(0, __float_as_int(x), 0x124, 0xf, 0xf, true); x += __int_as_float(_t); } \
  { int _t = __builtin_amdgcn_update_dpp(0, __float_as_int(x), 0x128, 0xf, 0xf, true); x += __int_as_float(_t); } }

// ---------------- kernel 0: weight prep (transpose -> bf16) ----------------
__global__ __launch_bounds__(256) void prep_kernel(
    const float* __restrict__ Wq, const float* __restrict__ Wk, const float* __restrict__ Wv,
    const float* __restrict__ Wo, const float* __restrict__ bq, const float* __restrict__ bk,
    const float* __restrict__ bv,
    unsigned short* __restrict__ Wt, unsigned short* __restrict__ Wot, float* __restrict__ bqkv)
{
  int idx = blockIdx.x * 256 + threadIdx.x;
  if (idx < 192 * 1024) {
    int n = idx >> 10, k = idx & 1023;
    const float* W = (n < 64) ? Wq : (n < 128) ? Wk : Wv;
    Wt[idx] = f2bf(W[k * 64 + (n & 63)]);
  } else if (idx < 192 * 1024 + 1024 * 64) {
    int j = idx - 192 * 1024;
    int n = j >> 6, k = j & 63;
    Wot[j] = f2bf(Wo[k * 1024 + n]);
  } else if (idx < 192 * 1024 + 1024 * 64 + 192) {
    int n = idx - (192 * 1024 + 1024 * 64);
    bqkv[n] = (n < 64) ? bq[n] : (n < 128) ? bk[n - 64] : bv[n - 128];
  }
}

// ---------------- kernel 1: QKV projection (bf16 MFMA), 2-deep pipeline ----------------
// X [16384][1024] fp32, Wt [192][1024] bf16 -> qkvb [16384][192] bf16
// BM=32, BN=96 (N split in 2), BK=64; grid 1024 -> 4 blocks/CU.
// Distance-2 register prefetch: two named reg sets (E/O), ping-pong LDS buffers,
// ONE barrier per K-step. In-flight window ~2 iterations > HBM latency.
#define QKV_STORE(BUF, A0, A1, B0, B1, B2) { \
  uint4 pv_; \
  pv_.x = pk2(A0.x, A0.y); pv_.y = pk2(A0.z, A0.w); \
  pv_.z = pk2(A1.x, A1.y); pv_.w = pk2(A1.z, A1.w); \
  *(uint4*)(As[BUF] + rowA * 72 + cA * 8) = pv_; \
  *(uint4*)(Bs[BUF] + rowA * 72 + cA * 8) = B0; \
  *(uint4*)(Bs[BUF] + (rowA + 32) * 72 + cA * 8) = B1; \
  *(uint4*)(Bs[BUF] + (rowA + 64) * 72 + cA * 8) = B2; }

#define QKV_LOAD(KS, A0, A1, B0, B1, B2) { \
  const float* sA_ = srcA + (KS) * 64; \
  A0 = *(const float4*)(sA_); A1 = *(const float4*)(sA_ + 4); \
  const unsigned short* sB_ = srcB + (KS) * 64; \
  B0 = *(const uint4*)(sB_); \
  B1 = *(const uint4*)(sB_ + 32 * 1024); \
  B2 = *(const uint4*)(sB_ + 64 * 1024); }

#define QKV_MMA(BUF) { \
  _Pragma("unroll") \
  for (int kk = 0; kk < 64; kk += 32) { \
    int ko = kk + quad * 8; \
    bf16x8 afr = *(const bf16x8*)(As[BUF] + (mg * 16 + col) * 72 + ko); \
    _Pragma("unroll") \
    for (int ns = 0; ns < 3; ++ns) { \
      bf16x8 bfr = *(const bf16x8*)(Bs[BUF] + ((ng * 3 + ns) * 16 + col) * 72 + ko); \
      acc[ns] = __builtin_amdgcn_mfma_f32_16x16x32_bf16(afr, bfr, acc[ns], 0, 0, 0); \
    } } }

__global__ __launch_bounds__(256) void qkv_gemm(
    const float* __restrict__ X, const unsigned short* __restrict__ Wt,
    const float* __restrict__ bqkv, unsigned short* __restrict__ qkvb)
{
  __shared__ __align__(16) unsigned short As[2][32 * 72];
  __shared__ __align__(16) unsigned short Bs[2][96 * 72];
  int t = threadIdx.x;
  int lane = t & 63, w = t >> 6;
  int m0 = (blockIdx.x >> 1) * 32;
  int nbase = (blockIdx.x & 1) * 96;
  int mg = w & 1, ng = w >> 1;               // wave: 16 rows x 48 cols
  int col = lane & 15, quad = lane >> 4;
  f32x4 acc[3] = {};

  int rowA = t >> 3, cA = t & 7;
  const float* srcA = X + (size_t)(m0 + rowA) * 1024 + cA * 8;
  const unsigned short* srcB = Wt + (size_t)(nbase + rowA) * 1024 + cA * 8;

  float4 eA0, eA1; uint4 eB0, eB1, eB2;      // even tiles
  float4 oA0, oA1; uint4 oB0, oB1, oB2;      // odd tiles
  QKV_LOAD(0, eA0, eA1, eB0, eB1, eB2);
  QKV_LOAD(1, oA0, oA1, oB0, oB1, oB2);

  for (int ks = 0; ks < 16; ks += 2) {
    QKV_STORE(0, eA0, eA1, eB0, eB1, eB2);
    if (ks + 2 < 16) QKV_LOAD(ks + 2, eA0, eA1, eB0, eB1, eB2);
    __syncthreads();
    QKV_MMA(0);
    // race-free: MMA(1) of prev iter (reads Bs[1]) is separated from this
    // STORE(1) by the even barrier above.
    QKV_STORE(1, oA0, oA1, oB0, oB1, oB2);
    if (ks + 3 < 16) QKV_LOAD(ks + 3, oA0, oA1, oB0, oB1, oB2);
    __syncthreads();
    QKV_MMA(1);
  }
  #pragma unroll
  for (int ns = 0; ns < 3; ++ns)
    #pragma unroll
    for (int r = 0; r < 4; ++r) {
      int m = m0 + mg * 16 + quad * 4 + r;
      int n = nbase + ng * 48 + ns * 16 + col;
      qkvb[(size_t)m * 192 + n] = f2bf(acc[ns][r] + bqkv[n]);
    }
}

// ---------------- kernel 2: banded flash attention (MFMA), 8 waves ----------------
// 512 threads; wave-pairs (p = w>>1) own 16 q-rows; s = w&1 splits the
// 9 j-tiles (5+4) and 5 PV k-chunks (3+2). Cross-wave max/sum/O via LDS.
// Exact: out-of-band exp underflows to 0; padding mask softmax-invariant.
__global__ __launch_bounds__(512) void band_attn(
    const unsigned short* __restrict__ qkvb, const float* __restrict__ bias,
    unsigned short* __restrict__ attnout)
{
  __shared__ __align__(16) unsigned short Kl[192 * 72];
  __shared__ __align__(16) unsigned short Vt[64 * 216];
  __shared__ __align__(16) unsigned short Ps[4 * 16 * 168];
  __shared__ float Osum[4][16][64];
  __shared__ float Mx[8][16];
  __shared__ float Lx[8][16];
  __shared__ float biasL[129];

  int t = threadIdx.x;
  int lane = t & 63, w = t >> 6;
  int p = w >> 1, s = w & 1;
  int col = lane & 15, quad = lane >> 4, q4 = quad * 4;
  int bidx = blockIdx.x;
  int b = bidx >> 5;                 // batch
  int i0 = (bidx & 31) * 64;         // first q row (batch coords)
  int jw = i0 - 64;                  // window start (may be <0)
  const unsigned short* qbase = qkvb + (size_t)(b << 11) * 192;

  // Q fragments: issue global loads FIRST so they overlap the staging loop
  int iq = i0 + p * 16;                    // pair's first q row (batch coords)
  const unsigned short* qr = qbase + (size_t)(iq + col) * 192 + quad * 8;
  bf16x8 aq0 = *(const bf16x8*)(qr);
  bf16x8 aq1 = *(const bf16x8*)(qr + 32);

  if (t < 129) biasL[t] = bias[1984 + t];
  // stage window: 192 rows x (64 K + 64 V) bf16 = 16 chunks of 16B per row
  #pragma unroll
  for (int it = 0; it < 6; ++it) {
    int idx = it * 512 + t;
    int row = idx >> 4;                    // 0..191 window row
    int c = idx & 15;                      // 16B chunk within k|v
    int jb = jw + row;
    int jc = jb < 0 ? 0 : (jb > 2047 ? 2047 : jb);
    const unsigned short* src = qbase + (size_t)jc * 192 + 64 + c * 8;
    uint4 v = *(const uint4*)src;
    if (c < 8) {                           // K: direct copy
      *(uint4*)(Kl + row * 72 + c * 8) = v;
    } else {                               // V: transpose store
      union { uint4 u; unsigned short ss[8]; } uv; uv.u = v;
      int p0 = (c - 8) * 8;
      #pragma unroll
      for (int e = 0; e < 8; ++e) Vt[(p0 + e) * 216 + row] = uv.ss[e];
    }
  }
  if (t < 256) { // zero-fill Vt j-cols 192..207 (PV k-chunk overhang)
    int pz = t >> 2, c0 = 192 + (t & 3) * 4;
    *(uint2*)(Vt + pz * 216 + c0) = make_uint2(0u, 0u);
  }
  __syncthreads();

  // QK^T: wave's j-tile subset (s=0: t9 0..4, s=1: t9 5..8)
  int nt9 = 5 - s, t9b = 5 * s;
  f32x4 sv[5];
  for (int i = 0; i < nt9; ++i) {
    int t9 = t9b + i;
    int krow = ((p + t9) * 16 + col) * 72;
    bf16x8 kb0 = *(const bf16x8*)(Kl + krow + quad * 8);
    bf16x8 kb1 = *(const bf16x8*)(Kl + krow + 32 + quad * 8);
    f32x4 z = {};
    z = __builtin_amdgcn_mfma_f32_16x16x32_bf16(aq0, kb0, z, 0, 0, 0);
    sv[i] = __builtin_amdgcn_mfma_f32_16x16x32_bf16(aq1, kb1, z, 0, 0, 0);
  }
  // mask + bias; partial row max
  float mrow[4] = {-3e38f, -3e38f, -3e38f, -3e38f};
  for (int i = 0; i < nt9; ++i) {
    int t9 = t9b + i;
    int j = iq - 64 + t9 * 16 + col;       // batch coords
    #pragma unroll
    for (int r = 0; r < 4; ++r) {
      int diff = q4 + r + 64 - t9 * 16 - col;   // i - j
      bool valid = (j >= 0) & (j < 2048) & (diff >= -64) & (diff <= 64);
      int bi = 64 - diff; bi = bi < 0 ? 0 : (bi > 128 ? 128 : bi);
      float x = valid ? (sv[i][r] * 0.125f + biasL[bi]) : -3e38f;
      sv[i][r] = x;
      mrow[r] = fmaxf(mrow[r], x);
    }
  }
  #pragma unroll
  for (int r = 0; r < 4; ++r) ROW16_MAX(mrow[r]);
  if (col == 0) {
    #pragma unroll
    for (int r = 0; r < 4; ++r) Mx[w][q4 + r] = mrow[r];
  }
  __syncthreads();
  #pragma unroll
  for (int r = 0; r < 4; ++r) mrow[r] = fmaxf(mrow[r], Mx[w ^ 1][q4 + r]);

  unsigned short* Pw = Ps + p * (16 * 168);
  float lsum[4] = {0.f, 0.f, 0.f, 0.f};
  for (int i = 0; i < nt9; ++i) {
    int t9 = t9b + i;
    #pragma unroll
    for (int r = 0; r < 4; ++r) {
      float pe = __expf(sv[i][r] - mrow[r]);
      lsum[r] += pe;
      Pw[(q4 + r) * 168 + t9 * 16 + col] = f2bf(pe);
    }
  }
  #pragma unroll
  for (int r = 0; r < 4; ++r) ROW16_SUM(lsum[r]);
  if (col == 0) {
    #pragma unroll
    for (int r = 0; r < 4; ++r) Lx[w][q4 + r] = lsum[r];
  }
  if (s == 0) {
    #pragma unroll
    for (int r = 0; r < 4; ++r) Pw[(q4 + r) * 168 + 144 + col] = 0;
  }
  __syncthreads();
  #pragma unroll
  for (int r = 0; r < 4; ++r) lsum[r] += Lx[w ^ 1][q4 + r];

  // PV: wave's k-chunk subset (s=0: kc 0..2, s=1: kc 3..4)
  f32x4 o[4] = {};
  int nkc = 3 - s, kcb = 3 * s;
  for (int i = 0; i < nkc; ++i) {
    int kc = kcb + i;
    bf16x8 pa = *(const bf16x8*)(Pw + col * 168 + kc * 32 + quad * 8);
    #pragma unroll
    for (int nt = 0; nt < 4; ++nt) {
      bf16x8 vb = *(const bf16x8*)(Vt + (nt * 16 + col) * 216 + 16 * p + kc * 32 + quad * 8);
      o[nt] = __builtin_amdgcn_mfma_f32_16x16x32_bf16(pa, vb, o[nt], 0, 0, 0);
    }
  }
  if (s == 1) {
    #pragma unroll
    for (int nt = 0; nt < 4; ++nt)
      #pragma unroll
      for (int r = 0; r < 4; ++r)
        Osum[p][q4 + r][nt * 16 + col] = o[nt][r];
  }
  __syncthreads();
  if (s == 0) {
    float rl[4];
    #pragma unroll
    for (int r = 0; r < 4; ++r) rl[r] = 1.0f / lsum[r];
    #pragma unroll
    for (int nt = 0; nt < 4; ++nt)
      #pragma unroll
      for (int r = 0; r < 4; ++r) {
        int arow = (b << 11) + iq + q4 + r;
        attnout[(size_t)arow * 64 + nt * 16 + col] =
            f2bf((o[nt][r] + Osum[p][q4 + r][nt * 16 + col]) * rl[r]);
      }
  }
}

// ---------------- kernel 3: output projection (bf16 MFMA) + bias ----------------
__global__ __launch_bounds__(256) void out_gemm(
    const unsigned short* __restrict__ attn, const unsigned short* __restrict__ Wot,
    const float* __restrict__ bo, float* __restrict__ out)
{
  __shared__ __align__(16) unsigned short As[64 * 72];
  __shared__ __align__(16) unsigned short Bs[128 * 72];
  int t = threadIdx.x, lane = t & 63, w = t >> 6;
  int m0 = (blockIdx.x >> 3) * 64;
  int n0 = (blockIdx.x & 7) * 128;
  #pragma unroll
  for (int r = 0; r < 2; ++r) {            // stage A: 64x64 bf16
    int tau = t + 256 * r; int row = tau >> 3, c = tau & 7;
    *(uint4*)(As + row * 72 + c * 8) =
        *(const uint4*)(attn + (size_t)(m0 + row) * 64 + c * 8);
  }
  #pragma unroll
  for (int r = 0; r < 4; ++r) {            // stage B: 128x64 bf16
    int tau = t + 256 * r; int n = tau >> 3, c = tau & 7;
    *(uint4*)(Bs + n * 72 + c * 8) =
        *(const uint4*)(Wot + (size_t)(n0 + n) * 64 + c * 8);
  }
  __syncthreads();
  f32x4 acc[2][4] = {};
  int mg = w & 1, ngg = w >> 1;
  #pragma unroll
  for (int kk = 0; kk < 64; kk += 32) {
    int ko = kk + (lane >> 4) * 8;
    bf16x8 a0 = *(const bf16x8*)(As + (mg * 32 +      (lane & 15)) * 72 + ko);
    bf16x8 a1 = *(const bf16x8*)(As + (mg * 32 + 16 + (lane & 15)) * 72 + ko);
    #pragma unroll
    for (int ns = 0; ns < 4; ++ns) {
      bf16x8 b = *(const bf16x8*)(Bs + ((ngg * 4 + ns) * 16 + (lane & 15)) * 72 + ko);
      acc[0][ns] = __builtin_amdgcn_mfma_f32_16x16x32_bf16(a0, b, acc[0][ns], 0, 0, 0);
      acc[1][ns] = __builtin_amdgcn_mfma_f32_16x16x32_bf16(a1, b, acc[1][ns], 0, 0, 0);
    }
  }
  int col = lane & 15, q = lane >> 4;
  #pragma unroll
  for (int ms = 0; ms < 2; ++ms)
    #pragma unroll
    for (int ns = 0; ns < 4; ++ns)
      #pragma unroll
      for (int r = 0; r < 4; ++r) {
        int mm = m0 + mg * 32 + ms * 16 + q * 4 + r;
        int nn = n0 + (ngg * 4 + ns) * 16 + col;
        out[(size_t)mm * 1024 + nn] = acc[ms][ns][r] + bo[nn];
      }
}

// ---------------- launch ----------------
extern "C" void kernel_launch(void* const* d_in, const int* in_sizes, int n_in,
                              void* d_out, int out_size, void* d_ws, size_t ws_size,
                              hipStream_t stream) {
  const float* X    = (const float*)d_in[0];
  // d_in[1] = attention_mask: per-row constant shift -> softmax-invariant, unused
  const float* Wq   = (const float*)d_in[2];
  const float* bq   = (const float*)d_in[3];
  const float* Wk   = (const float*)d_in[4];
  const float* bk   = (const float*)d_in[5];
  const float* Wv   = (const float*)d_in[6];
  const float* bv   = (const float*)d_in[7];
  const float* Wo   = (const float*)d_in[8];
  const float* bo   = (const float*)d_in[9];
  const float* bias = (const float*)d_in[10];
  float* out = (float*)d_out;
  char* ws = (char*)d_ws;
  unsigned short* qkvb = (unsigned short*)(ws);              // 6,291,456 B
  unsigned short* attn = (unsigned short*)(ws + 6291456);    // 2,097,152 B
  unsigned short* Wt   = (unsigned short*)(ws + 8388608);    //   393,216 B
  unsigned short* Wot  = (unsigned short*)(ws + 8781824);    //   131,072 B
  float*          bqkv = (float*)(ws + 8912896);             //       768 B

  prep_kernel<<<1025, 256, 0, stream>>>(Wq, Wk, Wv, Wo, bq, bk, bv, Wt, Wot, bqkv);
  qkv_gemm<<<1024, 256, 0, stream>>>(X, Wt, bqkv, qkvb);
  band_attn<<<256, 512, 0, stream>>>(qkvb, bias, attn);
  out_gemm<<<2048, 256, 0, stream>>>(attn, Wot, bo, out);
}